// Round 3
// baseline (726.133 us; speedup 1.0000x reference)
//
#include <hip/hip_runtime.h>
#include <hip/hip_fp16.h>
#include <hip/hip_cooperative_groups.h>
#include <cstddef>
#include <cstdint>

namespace cg = cooperative_groups;

#define BATCH 32

// Workspace layout (floats) — identical to round-1:
//   Xh : [16384][32] half4 (node-major)            = 1,048,576 floats
//   Th : layer0: 5 slices [n][32] half4; layers1-3: [n][32][32] halves
//        region = 10,485,760 floats
//   X1 : 4,194,304   X2 : 1,048,576   X3 : 262,144
//   X4 : 131,072 ([32][64][64] = [b][m][f])        P : 65,536

struct alignas(8) half4 { __half2 lo, hi; };

__device__ __forceinline__ void h4f(const half4 h, float f[4]) {
  float2 a = __half22float2(h.lo);
  float2 c = __half22float2(h.hi);
  f[0] = a.x; f[1] = a.y; f[2] = c.x; f[3] = c.y;
}
__device__ __forceinline__ void fma4(float4& a, float s, const float4& w) {
  a.x += s * w.x; a.y += s * w.y; a.z += s * w.z; a.w += s * w.w;
}
__device__ __forceinline__ float4 relu4(const float4& a) {
  return make_float4(fmaxf(a.x, 0.f), fmaxf(a.y, 0.f), fmaxf(a.z, 0.f), fmaxf(a.w, 0.f));
}

// ============================================================================
// Device-side stage bodies (shared by mega kernel; fallback kernels re-code)
// ============================================================================

__device__ __forceinline__ void d_transpose_cell(
    const float* __restrict__ x, half4* __restrict__ xh, int t)
{
  int n = t >> 5;
  int b = t & 31;
  const float* src = x + ((size_t)b * 16384 + n) * 3;
  half4 h;
  h.lo = __floats2half2_rn(src[0], src[1]);
  h.hi = __floats2half2_rn(src[2], 0.f);
  xh[t] = h;
}

__device__ __forceinline__ void d_cheb_cell(
    const half4* __restrict__ Tin, const half4* __restrict__ Tpp,
    const int* __restrict__ ec, half4* __restrict__ Tout,
    float coef, float beta, int idx)
{
  int n = idx >> 5;
  const int2* e2 = (const int2*)(ec + n * 6);
  int2 ea = e2[0], eb = e2[1], ez = e2[2];
  int na[6];
  na[0] = ea.x; na[1] = ea.y; na[2] = eb.x;
  na[3] = eb.y; na[4] = ez.x; na[5] = ez.y;
  int b = idx & 31;
  float s0 = 0.f, s1 = 0.f, s2 = 0.f;
#pragma unroll
  for (int d = 0; d < 6; ++d) {
    half4 v = Tin[(na[d] << 5) | b];
    float2 a = __half22float2(v.lo);
    float2 c = __half22float2(v.hi);
    s0 += a.x; s1 += a.y; s2 += c.x;
  }
  half4 p = Tpp[idx];
  float2 pa = __half22float2(p.lo);
  float2 pc = __half22float2(p.hi);
  half4 o;
  o.lo = __floats2half2_rn(coef * s0 + beta * pa.x, coef * s1 + beta * pa.y);
  o.hi = __floats2half2_rn(coef * s2 + beta * pc.x, 0.f);
  Tout[idx] = o;
}

// pool(relu(conv)) FIN=3 cell; Ws in LDS, node-major Xh/T
__device__ __forceinline__ void d_poolf3_cell(
    const half4* __restrict__ Xh, const half4* __restrict__ T,
    const float* __restrict__ Ws, const float* __restrict__ bias,
    const int* __restrict__ pc, const float* __restrict__ pv,
    float* __restrict__ out, int t)
{
  constexpr int F4 = 8;                        // FOUT=32
  constexpr size_t SL = (size_t)16384 * 32;
  const float4* Ws4 = (const float4*)Ws;
  int fo4 = t % F4;
  int b   = (t / F4) % BATCH;
  int m   = t / (F4 * BATCH);
  int c0 = pc[m * 3 + 0], c1 = pc[m * 3 + 1], c2 = pc[m * 3 + 2];
  float v0 = pv[m * 3 + 0], v1 = pv[m * 3 + 1], v2 = pv[m * 3 + 2];
  float4 bi = ((const float4*)bias)[fo4];
  float4 a0 = bi, a1 = bi, a2 = bi;
#pragma unroll
  for (int k = 0; k < 6; ++k) {
    const half4* base = (k == 0) ? Xh : (T + (size_t)(k - 1) * SL);
    float r0[4], r1[4], r2[4];
    h4f(base[(c0 << 5) | b], r0);
    h4f(base[(c1 << 5) | b], r1);
    h4f(base[(c2 << 5) | b], r2);
#pragma unroll
    for (int f = 0; f < 3; ++f) {
      float4 w = Ws4[(k * 3 + f) * F4 + fo4];
      fma4(a0, r0[f], w);
      fma4(a1, r1[f], w);
      fma4(a2, r2[f], w);
    }
  }
  a0 = relu4(a0); a1 = relu4(a1); a2 = relu4(a2);
  float4 acc;
  acc.x = v0*a0.x + v1*a1.x + v2*a2.x;
  acc.y = v0*a0.y + v1*a1.y + v2*a2.y;
  acc.z = v0*a0.z + v1*a1.z + v2*a2.z;
  acc.w = v0*a0.w + v1*a1.w + v2*a2.w;
  ((float4*)out)[((size_t)m * BATCH + b) * F4 + fo4] = acc;
}

// pool(relu(conv)) FIN=32 cell
template<int N, int M, int FOUT, bool OUT_BM>
__device__ __forceinline__ void d_pool32_cell(
    const float* __restrict__ X, const __half* __restrict__ Th,
    const float* __restrict__ Ws, const float* __restrict__ bias,
    const int* __restrict__ pc, const float* __restrict__ pv,
    float* __restrict__ out, int t)
{
  constexpr int F4 = FOUT / 4;
  constexpr size_t SLH = (size_t)N * 32 * 32;
  const float4* Ws4 = (const float4*)Ws;
  const float4* X4p = (const float4*)X;
  int fo4 = t % F4;
  int b   = (t / F4) % BATCH;
  int m   = t / (F4 * BATCH);
  int c0 = pc[m * 3 + 0], c1 = pc[m * 3 + 1], c2 = pc[m * 3 + 2];
  float v0 = pv[m * 3 + 0], v1 = pv[m * 3 + 1], v2 = pv[m * 3 + 2];
  float4 bi = ((const float4*)bias)[fo4];
  float4 a0 = bi, a1 = bi, a2 = bi;
  {
    const float4* r0 = X4p + ((size_t)c0 * BATCH + b) * 8;
    const float4* r1 = X4p + ((size_t)c1 * BATCH + b) * 8;
    const float4* r2 = X4p + ((size_t)c2 * BATCH + b) * 8;
#pragma unroll
    for (int fi = 0; fi < 8; ++fi) {
      float4 t0 = r0[fi], t1 = r1[fi], t2 = r2[fi];
#pragma unroll
      for (int ff = 0; ff < 4; ++ff) {
        float4 w = Ws4[(fi * 4 + ff) * F4 + fo4];
        fma4(a0, ((const float*)&t0)[ff], w);
        fma4(a1, ((const float*)&t1)[ff], w);
        fma4(a2, ((const float*)&t2)[ff], w);
      }
    }
  }
#pragma unroll 1
  for (int k = 1; k < 6; ++k) {
    const half4* base = (const half4*)(Th + (size_t)(k - 1) * SLH);
    const half4* r0 = base + ((size_t)c0 * 32 + b) * 8;
    const half4* r1 = base + ((size_t)c1 * 32 + b) * 8;
    const half4* r2 = base + ((size_t)c2 * 32 + b) * 8;
#pragma unroll
    for (int q = 0; q < 8; ++q) {
      float f0[4], f1[4], f2[4];
      h4f(r0[q], f0); h4f(r1[q], f1); h4f(r2[q], f2);
#pragma unroll
      for (int ff = 0; ff < 4; ++ff) {
        float4 w = Ws4[((k * 32) + q * 4 + ff) * F4 + fo4];
        fma4(a0, f0[ff], w);
        fma4(a1, f1[ff], w);
        fma4(a2, f2[ff], w);
      }
    }
  }
  a0 = relu4(a0); a1 = relu4(a1); a2 = relu4(a2);
  float4 acc;
  acc.x = v0*a0.x + v1*a1.x + v2*a2.x;
  acc.y = v0*a0.y + v1*a1.y + v2*a2.y;
  acc.z = v0*a0.z + v1*a1.z + v2*a2.z;
  acc.w = v0*a0.w + v1*a1.w + v2*a2.w;
  size_t oi = OUT_BM ? (((size_t)b * M + m) * F4 + fo4) : (((size_t)m * BATCH + b) * F4 + fo4);
  ((float4*)out)[oi] = acc;
}

// LDS-resident Cheb recurrence stage (layers 1-3), half4 cells, 512-thread flavor
template<int N, int NPT>
__device__ void d_recur_stage(
    const float* __restrict__ X, const int* __restrict__ ec,
    __half* __restrict__ Th, half4* cur, int bid, int tid)
{
  const float cI = -1.0f / 6.0f;
  const float cS = -1.0f / 3.0f;
  const int b = bid & 31;
  const int fbase = (bid >> 5) * 4;
  constexpr size_t SLH = (size_t)N * 32 * 32;
  half4 prevv[NPT], newh[NPT];
#pragma unroll
  for (int i = 0; i < NPT; ++i) {
    int n = tid + i * 512;
    if (n < N) {
      float4 xv = *(const float4*)(X + ((size_t)n * 32 + b) * 32 + fbase);
      half4 h;
      h.lo = __floats2half2_rn(xv.x, xv.y);
      h.hi = __floats2half2_rn(xv.z, xv.w);
      cur[n] = h;
    }
  }
  __syncthreads();
#pragma unroll 1
  for (int k = 1; k <= 5; ++k) {
    __half* Tk = Th + (size_t)(k - 1) * SLH;
#pragma unroll
    for (int i = 0; i < NPT; ++i) {
      int n = tid + i * 512;
      if (n < N) {
        const int2* e2 = (const int2*)(ec + n * 6);
        int2 ea = e2[0], eb = e2[1], ez = e2[2];
        int na[6];
        na[0] = ea.x; na[1] = ea.y; na[2] = eb.x;
        na[3] = eb.y; na[4] = ez.x; na[5] = ez.y;
        float s0 = 0.f, s1 = 0.f, s2 = 0.f, s3 = 0.f;
#pragma unroll
        for (int d = 0; d < 6; ++d) {
          half4 t = cur[na[d]];
          float2 a = __half22float2(t.lo);
          float2 c = __half22float2(t.hi);
          s0 += a.x; s1 += a.y; s2 += c.x; s3 += c.y;
        }
        float v0, v1, v2, v3;
        if (k == 1) {
          v0 = cI * s0; v1 = cI * s1; v2 = cI * s2; v3 = cI * s3;
        } else {
          float2 pa = __half22float2(prevv[i].lo);
          float2 pc = __half22float2(prevv[i].hi);
          v0 = cS * s0 - pa.x; v1 = cS * s1 - pa.y;
          v2 = cS * s2 - pc.x; v3 = cS * s3 - pc.y;
        }
        half4 h;
        h.lo = __floats2half2_rn(v0, v1);
        h.hi = __floats2half2_rn(v2, v3);
        newh[i] = h;
        *(half4*)(Tk + ((size_t)n * 32 + b) * 32 + fbase) = h;
      }
    }
    __syncthreads();
#pragma unroll
    for (int i = 0; i < NPT; ++i) {
      int n = tid + i * 512;
      if (n < N) {
        prevv[i] = cur[n];
        cur[n] = newh[i];
      }
    }
    __syncthreads();
  }
}

// ============================================================================
// MEGA cooperative kernel: the entire network, grid.sync between stages.
// 256 blocks x 512 threads (1 block/CU), 48 KB LDS union.
// ============================================================================

struct MegaP {
  const float* x;
  const int *ec0, *ec1, *ec2, *ec3;
  const int *pc0, *pc1, *pc2, *pc3;
  const float *pv0, *pv1, *pv2, *pv3;
  const float *W0, *b0, *W1, *b1, *W2, *b2, *W3, *b3;
  const float *encW, *encB, *clsW, *clsB;
  float* out;
  half4* Xh; __half* Th;
  float *X1, *X2, *X3, *X4, *P;
};

__global__ void __launch_bounds__(512, 2) mega(MegaP P)
{
  cg::grid_group grid = cg::this_grid();
  __shared__ __align__(16) char smemraw[49152];   // 48 KB union
  half4* scur = (half4*)smemraw;
  float* sws  = (float*)smemraw;
  const int bid = blockIdx.x;     // 0..255
  const int tid = threadIdx.x;    // 0..511
  const float cI = -1.0f / 6.0f;
  const float cS = -1.0f / 3.0f;

  // ---- stage T: transpose x -> Xh (524288 cells, 4 iters) ----
#pragma unroll
  for (int u = 0; u < 4; ++u)
    d_transpose_cell(P.x, P.Xh, u * 131072 + bid * 512 + tid);
  grid.sync();

  // ---- stages C1..C5: layer-0 Cheb chain (node-major, L2-resident) ----
  {
    const size_t S = (size_t)16384 * 32;
    half4* T4 = (half4*)P.Th;
    const half4* Tin[5] = { P.Xh, T4, T4 + S, T4 + 2*S, T4 + 3*S };
    const half4* Tpp[5] = { P.Xh, P.Xh, T4, T4 + S, T4 + 2*S };
    half4* Tout[5]      = { T4, T4 + S, T4 + 2*S, T4 + 3*S, T4 + 4*S };
#pragma unroll 1
    for (int k = 0; k < 5; ++k) {
      float coef = (k == 0) ? cI : cS;
      float beta = (k == 0) ? 0.f : -1.f;
#pragma unroll
      for (int u = 0; u < 4; ++u)
        d_cheb_cell(Tin[k], Tpp[k], P.ec0, Tout[k], coef, beta,
                    u * 131072 + bid * 512 + tid);
      grid.sync();
    }
  }

  // ---- stage P0: pool(relu(conv)) layer 0 (1,048,576 cells, 8 iters) ----
  for (int i = tid; i < 6 * 3 * 32; i += 512) sws[i] = P.W0[i];
  __syncthreads();
#pragma unroll 1
  for (int u = 0; u < 8; ++u)
    d_poolf3_cell(P.Xh, (const half4*)P.Th, sws, P.b0, P.pc0, P.pv0, P.X1,
                  u * 131072 + bid * 512 + tid);
  grid.sync();

  // ---- stage R1: recurrence layer 1 (N=4096) ----
  d_recur_stage<4096, 8>(P.X1, P.ec1, P.Th, scur, bid, tid);
  grid.sync();

  // ---- stage B1: pool layer 1 (M=1024, 262144 cells, 2 iters) ----
  for (int i = tid; i < 6 * 32 * 32; i += 512) sws[i] = P.W1[i];
  __syncthreads();
#pragma unroll 1
  for (int u = 0; u < 2; ++u)
    d_pool32_cell<4096, 1024, 32, false>(P.X1, P.Th, sws, P.b1, P.pc1, P.pv1,
                                         P.X2, u * 131072 + bid * 512 + tid);
  grid.sync();

  // ---- stage R2: recurrence layer 2 (N=1024) ----
  d_recur_stage<1024, 2>(P.X2, P.ec2, P.Th, scur, bid, tid);
  grid.sync();

  // ---- stage B2: pool layer 2 (M=256, 65536 cells) ----
  for (int i = tid; i < 6 * 32 * 32; i += 512) sws[i] = P.W2[i];
  __syncthreads();
  {
    int t = bid * 512 + tid;
    if (t < 65536)
      d_pool32_cell<1024, 256, 32, false>(P.X2, P.Th, sws, P.b2, P.pc2, P.pv2,
                                          P.X3, t);
  }
  grid.sync();

  // ---- stage R3: recurrence layer 3 (N=256) ----
  d_recur_stage<256, 1>(P.X3, P.ec3, P.Th, scur, bid, tid);
  grid.sync();

  // ---- stage B3: pool layer 3 (M=64, FOUT=64, 32768 cells, batch-major out) ----
  for (int i = tid; i < 6 * 32 * 64; i += 512) sws[i] = P.W3[i];
  __syncthreads();
  {
    int t = bid * 512 + tid;
    if (t < 32768)
      d_pool32_cell<256, 64, 64, true>(P.X3, P.Th, sws, P.b3, P.pc3, P.pv3,
                                       P.X4, t);
  }
  grid.sync();

  // ---- stage G: encoder split-K partials (65536 threads) ----
  {
    int t = bid * 512 + tid;
    if (t < 65536) {
      int fo = t & 127;
      int ks = (t >> 7) & 15;
      int b  = t >> 11;
      const float* xr = P.X4 + b * 4096 + ks * 256;
      const float* w  = P.encW + (size_t)(ks * 256) * 128 + fo;
      float acc = 0.f;
#pragma unroll 8
      for (int i = 0; i < 256; ++i) acc += xr[i] * w[(size_t)i * 128];
      P.P[(size_t)(b * 16 + ks) * 128 + fo] = acc;
    }
  }
  grid.sync();

  // ---- stage H: reduce + relu + classifier (32 blocks active) ----
  if (bid < 32) {
    int b = bid;
    float* hs = sws;
    if (tid < 128) {
      float acc = P.encB[tid];
#pragma unroll
      for (int ks = 0; ks < 16; ++ks)
        acc += P.P[(size_t)(b * 16 + ks) * 128 + tid];
      hs[tid] = fmaxf(acc, 0.f);
    }
    __syncthreads();
    if (tid < 10) {
      float s = P.clsB[tid];
#pragma unroll 4
      for (int f = 0; f < 128; ++f) s += hs[f] * P.clsW[f * 10 + tid];
      P.out[b * 10 + tid] = s;
    }
  }
}

// ============================================================================
// Fallback kernels (round-1 structure + verified recur_hh) — used only if the
// cooperative launch is rejected (e.g. capacity check).
// ============================================================================

__global__ void __launch_bounds__(256) transpose_h(
    const float* __restrict__ x, half4* __restrict__ xh)
{
  d_transpose_cell(x, xh, blockIdx.x * 256 + threadIdx.x);
}

__global__ void __launch_bounds__(256) cheb_step_h(
    const half4* __restrict__ Tin, const half4* __restrict__ Tpp,
    const int* __restrict__ ec, half4* __restrict__ Tout,
    float coef, float beta)
{
  d_cheb_cell(Tin, Tpp, ec, Tout, coef, beta, blockIdx.x * 256 + threadIdx.x);
}

__global__ void __launch_bounds__(256) pool_conv_f3_h(
    const half4* __restrict__ Xh, const half4* __restrict__ T,
    const float* __restrict__ W, const float* __restrict__ bias,
    const int* __restrict__ pc, const float* __restrict__ pv,
    float* __restrict__ out)
{
  __shared__ float Ws[6 * 3 * 32];
  for (int i = threadIdx.x; i < 6 * 3 * 32; i += 256) Ws[i] = W[i];
  __syncthreads();
  d_poolf3_cell(Xh, T, Ws, bias, pc, pv, out, blockIdx.x * 256 + threadIdx.x);
}

template<int N, int F, int THREADS, int MINW>
__global__ void __launch_bounds__(THREADS, MINW) cheb_recur_hh(
    const float* __restrict__ X, const int* __restrict__ ec,
    __half* __restrict__ Th)
{
  constexpr int NPT = N / THREADS;
  __shared__ half4 cur[N];
  const float cI = -1.0f / 6.0f;
  const float cS = -1.0f / 3.0f;
  const int b = blockIdx.x & 31;
  const int fbase = (blockIdx.x >> 5) * 4;
  constexpr size_t SLH = (size_t)N * 32 * F;
  half4 prevv[NPT], newh[NPT];
#pragma unroll
  for (int i = 0; i < NPT; ++i) {
    int n = threadIdx.x + i * THREADS;
    float4 xv = *(const float4*)(X + ((size_t)n * 32 + b) * F + fbase);
    half4 h;
    h.lo = __floats2half2_rn(xv.x, xv.y);
    h.hi = __floats2half2_rn(xv.z, xv.w);
    cur[n] = h;
  }
  __syncthreads();
#pragma unroll 1
  for (int k = 1; k <= 5; ++k) {
    __half* Tk = Th + (size_t)(k - 1) * SLH;
#pragma unroll
    for (int i = 0; i < NPT; ++i) {
      int n = threadIdx.x + i * THREADS;
      const int2* e2 = (const int2*)(ec + n * 6);
      int2 ea = e2[0], eb = e2[1], ez = e2[2];
      int na[6];
      na[0] = ea.x; na[1] = ea.y; na[2] = eb.x;
      na[3] = eb.y; na[4] = ez.x; na[5] = ez.y;
      float s0 = 0.f, s1 = 0.f, s2 = 0.f, s3 = 0.f;
#pragma unroll
      for (int d = 0; d < 6; ++d) {
        half4 t = cur[na[d]];
        float2 a = __half22float2(t.lo);
        float2 c = __half22float2(t.hi);
        s0 += a.x; s1 += a.y; s2 += c.x; s3 += c.y;
      }
      float v0, v1, v2, v3;
      if (k == 1) {
        v0 = cI * s0; v1 = cI * s1; v2 = cI * s2; v3 = cI * s3;
      } else {
        float2 pa = __half22float2(prevv[i].lo);
        float2 pc = __half22float2(prevv[i].hi);
        v0 = cS * s0 - pa.x; v1 = cS * s1 - pa.y;
        v2 = cS * s2 - pc.x; v3 = cS * s3 - pc.y;
      }
      half4 h;
      h.lo = __floats2half2_rn(v0, v1);
      h.hi = __floats2half2_rn(v2, v3);
      newh[i] = h;
      *(half4*)(Tk + ((size_t)n * 32 + b) * F + fbase) = h;
    }
    __syncthreads();
#pragma unroll
    for (int i = 0; i < NPT; ++i) {
      int n = threadIdx.x + i * THREADS;
      prevv[i] = cur[n];
      cur[n] = newh[i];
    }
    __syncthreads();
  }
}

template<int N, int M, int FOUT, bool OUT_BM>
__global__ void __launch_bounds__(256) pool_conv_v32_h(
    const float* __restrict__ X, const __half* __restrict__ Th,
    const float* __restrict__ W, const float* __restrict__ bias,
    const int* __restrict__ pc, const float* __restrict__ pv,
    float* __restrict__ out)
{
  __shared__ float Ws[6 * 32 * FOUT];
  for (int i = threadIdx.x; i < 6 * 32 * FOUT; i += 256) Ws[i] = W[i];
  __syncthreads();
  d_pool32_cell<N, M, FOUT, OUT_BM>(X, Th, Ws, bias, pc, pv, out,
                                    blockIdx.x * 256 + threadIdx.x);
}

__global__ void __launch_bounds__(256) encoder_partial(
    const float* __restrict__ Xf, const float* __restrict__ encW,
    float* __restrict__ partial)
{
  int b  = blockIdx.x;
  int ks = blockIdx.y;
  int fo = threadIdx.x & 127;
  int half = threadIdx.x >> 7;
  const float* xr = Xf + b * 4096 + ks * 256 + half * 128;
  const float* w  = encW + (size_t)(ks * 256 + half * 128) * 128;
  float acc = 0.f;
#pragma unroll 8
  for (int i = 0; i < 128; ++i) acc += xr[i] * w[(size_t)i * 128 + fo];
  __shared__ float part[256];
  part[threadIdx.x] = acc;
  __syncthreads();
  if (half == 0) partial[(size_t)(b * 16 + ks) * 128 + fo] = part[fo] + part[128 + fo];
}

__global__ void __launch_bounds__(128) encoder_reduce_cls(
    const float* __restrict__ partial, const float* __restrict__ encB,
    const float* __restrict__ clsW, const float* __restrict__ clsB,
    float* __restrict__ out)
{
  int b = blockIdx.x;
  int fo = threadIdx.x;
  float acc = encB[fo];
#pragma unroll
  for (int ks = 0; ks < 16; ++ks) acc += partial[(size_t)(b * 16 + ks) * 128 + fo];
  __shared__ float Hs[128];
  Hs[fo] = fmaxf(acc, 0.f);
  __syncthreads();
  if (fo < 10) {
    float s = clsB[fo];
#pragma unroll 4
    for (int f = 0; f < 128; ++f) s += Hs[f] * clsW[f * 10 + fo];
    out[b * 10 + fo] = s;
  }
}

// ============================================================================

extern "C" void kernel_launch(void* const* d_in, const int* in_sizes, int n_in,
                              void* d_out, int out_size, void* d_ws, size_t ws_size,
                              hipStream_t stream)
{
  const float* x   = (const float*)d_in[0];
  const int* ec0 = (const int*)d_in[2];
  const int* ec1 = (const int*)d_in[4];
  const int* ec2 = (const int*)d_in[6];
  const int* ec3 = (const int*)d_in[8];
  const int* pc0 = (const int*)d_in[10]; const float* pv0 = (const float*)d_in[11];
  const int* pc1 = (const int*)d_in[13]; const float* pv1 = (const float*)d_in[14];
  const int* pc2 = (const int*)d_in[16]; const float* pv2 = (const float*)d_in[17];
  const int* pc3 = (const int*)d_in[19]; const float* pv3 = (const float*)d_in[20];
  const float* W0 = (const float*)d_in[21]; const float* b0 = (const float*)d_in[22];
  const float* W1 = (const float*)d_in[23]; const float* b1 = (const float*)d_in[24];
  const float* W2 = (const float*)d_in[25]; const float* b2 = (const float*)d_in[26];
  const float* W3 = (const float*)d_in[27]; const float* b3 = (const float*)d_in[28];
  const float* encW = (const float*)d_in[29]; const float* encB = (const float*)d_in[30];
  const float* clsW = (const float*)d_in[31]; const float* clsB = (const float*)d_in[32];
  float* out = (float*)d_out;

  float* ws = (float*)d_ws;
  half4*  Xh = (half4*)ws;               // 1,048,576 floats
  __half* Th = (__half*)(ws + 1048576);  // 10,485,760 floats
  float* X1 = ws + 1048576 + 10485760;   // 4,194,304
  float* X2 = X1 + 4194304;              // 1,048,576
  float* X3 = X2 + 1048576;              // 262,144
  float* X4 = X3 + 262144;               // 131,072
  float* P  = X4 + 131072;               // 65,536

  MegaP mp;
  mp.x = x;
  mp.ec0 = ec0; mp.ec1 = ec1; mp.ec2 = ec2; mp.ec3 = ec3;
  mp.pc0 = pc0; mp.pc1 = pc1; mp.pc2 = pc2; mp.pc3 = pc3;
  mp.pv0 = pv0; mp.pv1 = pv1; mp.pv2 = pv2; mp.pv3 = pv3;
  mp.W0 = W0; mp.b0 = b0; mp.W1 = W1; mp.b1 = b1;
  mp.W2 = W2; mp.b2 = b2; mp.W3 = W3; mp.b3 = b3;
  mp.encW = encW; mp.encB = encB; mp.clsW = clsW; mp.clsB = clsB;
  mp.out = out;
  mp.Xh = Xh; mp.Th = Th;
  mp.X1 = X1; mp.X2 = X2; mp.X3 = X3; mp.X4 = X4; mp.P = P;

  void* kargs[] = { (void*)&mp };
  hipError_t e = hipLaunchCooperativeKernel((const void*)mega, dim3(256), dim3(512),
                                            kargs, 0, stream);
  if (e != hipSuccess) {
    (void)hipGetLastError();   // clear sticky error, run fallback path
    const float cI = -1.0f / 6.0f;
    const float cS = -1.0f / 3.0f;
    dim3 blk(256);
    transpose_h<<<dim3(2048), blk, 0, stream>>>(x, Xh);
    {
      constexpr size_t S = (size_t)16384 * 32;
      half4* T4 = (half4*)Th;
      cheb_step_h<<<dim3(2048), blk, 0, stream>>>(Xh,       Xh,       ec0, T4,        cI,  0.f);
      cheb_step_h<<<dim3(2048), blk, 0, stream>>>(T4,       Xh,       ec0, T4 + S,    cS, -1.f);
      cheb_step_h<<<dim3(2048), blk, 0, stream>>>(T4 + S,   T4,       ec0, T4 + 2*S,  cS, -1.f);
      cheb_step_h<<<dim3(2048), blk, 0, stream>>>(T4 + 2*S, T4 + S,   ec0, T4 + 3*S,  cS, -1.f);
      cheb_step_h<<<dim3(2048), blk, 0, stream>>>(T4 + 3*S, T4 + 2*S, ec0, T4 + 4*S,  cS, -1.f);
      pool_conv_f3_h<<<dim3(4096), blk, 0, stream>>>(
          Xh, (const half4*)Th, W0, b0, pc0, pv0, X1);
    }
    cheb_recur_hh<4096, 32, 1024, 4><<<dim3(256), dim3(1024), 0, stream>>>(X1, ec1, Th);
    pool_conv_v32_h<4096, 1024, 32, false><<<dim3(1024), blk, 0, stream>>>(
        X1, Th, W1, b1, pc1, pv1, X2);
    cheb_recur_hh<1024, 32, 256, 4><<<dim3(256), blk, 0, stream>>>(X2, ec2, Th);
    pool_conv_v32_h<1024, 256, 32, false><<<dim3(256), blk, 0, stream>>>(
        X2, Th, W2, b2, pc2, pv2, X3);
    cheb_recur_hh<256, 32, 256, 4><<<dim3(256), blk, 0, stream>>>(X3, ec3, Th);
    pool_conv_v32_h<256, 64, 64, true><<<dim3(128), blk, 0, stream>>>(
        X3, Th, W3, b3, pc3, pv3, X4);
    encoder_partial<<<dim3(32, 16), blk, 0, stream>>>(X4, encW, P);
    encoder_reduce_cls<<<dim3(32), dim3(128), 0, stream>>>(P, encB, clsW, clsB, out);
  }
}

// Round 4
// 283.454 us; speedup vs baseline: 2.5617x; 2.5617x over previous
//
#include <hip/hip_runtime.h>
#include <hip/hip_fp16.h>
#include <cstddef>
#include <cstdint>

#define BATCH 32

// Workspace layout (floats):
//   Xb : layer0 input, XCD-local layout [bg=8][16384][4] half4 = 1,048,576 floats
//   Th : layer0: 5 slices in [bg][16384][4] half4 layout;
//        layers1-3: node-major [n][32][F] halves (region reused)
//        region = 10,485,760 floats
//   X1 : 4,194,304   X2 : 1,048,576   X3 : 262,144
//   X4 : 131,072 ([32][4096] fp32, batch-major)   P : 65,536
//
// Layer-0 XCD locality: batch-group bg = b>>2 owns a contiguous 512 KB region
// per slice. All layer-0 kernels map bg = blockIdx.x & 7, so (empirical
// round-robin bid->XCD) producer and consumer of a bg-region run on the same
// XCD; gathers hit the local 4 MB L2 instead of L3. Correctness does not
// depend on the mapping.

struct alignas(8) half4 { __half2 lo, hi; };

__device__ __forceinline__ void h4f(const half4 h, float f[4]) {
  float2 a = __half22float2(h.lo);
  float2 c = __half22float2(h.hi);
  f[0] = a.x; f[1] = a.y; f[2] = c.x; f[3] = c.y;
}
__device__ __forceinline__ void fma4(float4& a, float s, const float4& w) {
  a.x += s * w.x; a.y += s * w.y; a.z += s * w.z; a.w += s * w.w;
}
__device__ __forceinline__ float4 relu4(const float4& a) {
  return make_float4(fmaxf(a.x, 0.f), fmaxf(a.y, 0.f), fmaxf(a.z, 0.f), fmaxf(a.w, 0.f));
}

// ---------------- transpose x[b][n][3] -> Xb[bg][n][b4] fp16 (pad=0) ----------------
// bid = q*8+bg; tid -> (nofs = tid>>2, b4 = tid&3); n = q*64+nofs.
__global__ void __launch_bounds__(256) transpose_b(
    const float* __restrict__ x, half4* __restrict__ xb)
{
  int bg = blockIdx.x & 7;
  int q  = blockIdx.x >> 3;
  int b4 = threadIdx.x & 3;
  int n  = q * 64 + (threadIdx.x >> 2);
  int b  = bg * 4 + b4;
  const float* src = x + ((size_t)b * 16384 + n) * 3;
  half4 h;
  h.lo = __floats2half2_rn(src[0], src[1]);
  h.hi = __floats2half2_rn(src[2], 0.f);
  xb[((size_t)(bg << 14) + n) * 4 + b4] = h;
}

// ---------------- fp16 Cheb step, layer 0, XCD-local ----------------
// One thread per (bg,n,b4) cell. Gather = [bg][e[d]][b4]: 4 lanes share a
// node -> 32 B contiguous segment, 16 segments/wave, all in bg's 512 KB
// region (local L2 if mapping holds).
__global__ void __launch_bounds__(256) cheb_step_b(
    const half4* __restrict__ Tin, const half4* __restrict__ Tpp,
    const int* __restrict__ ec, half4* __restrict__ Tout,
    float coef, float beta)
{
  int bg = blockIdx.x & 7;
  int q  = blockIdx.x >> 3;
  int b4 = threadIdx.x & 3;
  int n  = q * 64 + (threadIdx.x >> 2);
  const half4* Tb = Tin + ((size_t)bg << 16);     // bg * 16384 * 4
  const int2* e2 = (const int2*)(ec + n * 6);
  int2 ea = e2[0], eb = e2[1], ez = e2[2];
  int na[6];
  na[0] = ea.x; na[1] = ea.y; na[2] = eb.x;
  na[3] = eb.y; na[4] = ez.x; na[5] = ez.y;
  float s0 = 0.f, s1 = 0.f, s2 = 0.f;
#pragma unroll
  for (int d = 0; d < 6; ++d) {
    half4 v = Tb[(na[d] << 2) | b4];
    float2 a = __half22float2(v.lo);
    float2 c = __half22float2(v.hi);
    s0 += a.x; s1 += a.y; s2 += c.x;
  }
  size_t idx = ((size_t)(bg << 14) + n) * 4 + b4;
  half4 p = Tpp[idx];
  float2 pa = __half22float2(p.lo);
  float2 pc = __half22float2(p.hi);
  half4 o;
  o.lo = __floats2half2_rn(coef * s0 + beta * pa.x, coef * s1 + beta * pa.y);
  o.hi = __floats2half2_rn(coef * s2 + beta * pc.x, 0.f);
  Tout[idx] = o;
}

// ---------------- fused pool(relu(conv)), FIN=3, XCD-local fp16 X/T ----------------
// Block = (q,bg): 8 m x 4 b4 x 8 fo4. All gathers within bg's regions.
__global__ void __launch_bounds__(256) pool_conv_f3_b(
    const half4* __restrict__ Xb, const half4* __restrict__ T,   // slices [bg][16384][4]
    const float* __restrict__ W, const float* __restrict__ bias,
    const int* __restrict__ pc, const float* __restrict__ pv,
    float* __restrict__ out)
{
  constexpr int F4 = 8;                         // FOUT=32
  constexpr size_t SL = (size_t)16384 * 32;     // half4 per slice
  __shared__ float Ws[6 * 3 * 32];
  for (int i = threadIdx.x; i < 6 * 3 * 32; i += 256) Ws[i] = W[i];
  __syncthreads();
  const float4* Ws4 = (const float4*)Ws;
  int bg = blockIdx.x & 7;
  int q  = blockIdx.x >> 3;
  int fo4 = threadIdx.x & 7;
  int b4  = (threadIdx.x >> 3) & 3;
  int m   = q * 8 + (threadIdx.x >> 5);
  int b   = bg * 4 + b4;
  const size_t bgo = (size_t)bg << 16;          // bg * 16384 * 4
  int c0 = pc[m * 3 + 0], c1 = pc[m * 3 + 1], c2 = pc[m * 3 + 2];
  float v0 = pv[m * 3 + 0], v1 = pv[m * 3 + 1], v2 = pv[m * 3 + 2];
  float4 bi = ((const float4*)bias)[fo4];
  float4 a0 = bi, a1 = bi, a2 = bi;
#pragma unroll
  for (int k = 0; k < 6; ++k) {
    const half4* base = ((k == 0) ? Xb : (T + (size_t)(k - 1) * SL)) + bgo;
    float r0[4], r1[4], r2[4];
    h4f(base[(c0 << 2) | b4], r0);
    h4f(base[(c1 << 2) | b4], r1);
    h4f(base[(c2 << 2) | b4], r2);
#pragma unroll
    for (int f = 0; f < 3; ++f) {
      float4 w = Ws4[(k * 3 + f) * F4 + fo4];
      fma4(a0, r0[f], w);
      fma4(a1, r1[f], w);
      fma4(a2, r2[f], w);
    }
  }
  a0 = relu4(a0); a1 = relu4(a1); a2 = relu4(a2);
  float4 acc;
  acc.x = v0*a0.x + v1*a1.x + v2*a2.x;
  acc.y = v0*a0.y + v1*a1.y + v2*a2.y;
  acc.z = v0*a0.z + v1*a1.z + v2*a2.z;
  acc.w = v0*a0.w + v1*a1.w + v2*a2.w;
  ((float4*)out)[((size_t)m * BATCH + b) * F4 + fo4] = acc;   // node-major fp32
}

// ---------------- LDS-resident Cheb recurrence (layers 1-3, round-1 verified) ----------------
template<int N, int F, int THREADS, int MINW>
__global__ void __launch_bounds__(THREADS, MINW) cheb_recur_h4(
    const float* __restrict__ X,    // node-major fp32 [N][32][F]
    const int* __restrict__ ec,     // [N][6]
    __half* __restrict__ Th)        // 5 slices, [n][32][F] halves
{
  constexpr int NPT = N / THREADS;
  __shared__ float4 cur[N];                    // 16 B per node
  const float cI = -1.0f / 6.0f;
  const float cS = -1.0f / 3.0f;
  const int b = blockIdx.x & 31;
  const int fbase = (blockIdx.x >> 5) * 4;     // slab of 4 features
  constexpr size_t SLH = (size_t)N * 32 * F;   // halves per slice
  float4 prevv[NPT];
  // load T0 slab (float4)
#pragma unroll
  for (int i = 0; i < NPT; ++i) {
    int n = threadIdx.x + i * THREADS;
    cur[n] = *(const float4*)(X + ((size_t)n * 32 + b) * F + fbase);
  }
  __syncthreads();
#pragma unroll 1
  for (int k = 1; k <= 5; ++k) {
    float4 newv[NPT];
    __half* Tk = Th + (size_t)(k - 1) * SLH;
#pragma unroll
    for (int i = 0; i < NPT; ++i) {
      int n = threadIdx.x + i * THREADS;
      const int* e = ec + n * 6;
      float4 s = make_float4(0.f, 0.f, 0.f, 0.f);
#pragma unroll
      for (int d = 0; d < 6; ++d) {
        float4 t = cur[e[d]];                  // ds_read_b128
        s.x += t.x; s.y += t.y; s.z += t.z; s.w += t.w;
      }
      float4 v;
      if (k == 1) {
        v.x = cI * s.x; v.y = cI * s.y; v.z = cI * s.z; v.w = cI * s.w;
      } else {
        v.x = cS * s.x - prevv[i].x; v.y = cS * s.y - prevv[i].y;
        v.z = cS * s.z - prevv[i].z; v.w = cS * s.w - prevv[i].w;
      }
      newv[i] = v;
      half4 h;
      h.lo = __floats2half2_rn(v.x, v.y);
      h.hi = __floats2half2_rn(v.z, v.w);
      *(half4*)(Tk + ((size_t)n * 32 + b) * F + fbase) = h;
    }
    __syncthreads();   // all gathers of T_{k-1} complete
#pragma unroll
    for (int i = 0; i < NPT; ++i) {
      int n = threadIdx.x + i * THREADS;
      prevv[i] = cur[n];                       // own slot still = T_{k-1}
      cur[n] = newv[i];                        // T_k -> cur
    }
    __syncthreads();
  }
}

// ---------------- fused pool(relu(conv)), FIN=32, fp16 T (round-1 verified) ----------------
template<int N, int M, int FOUT, bool OUT_BM>
__global__ void __launch_bounds__(256) pool_conv_v32_h(
    const float* __restrict__ X, const __half* __restrict__ Th,
    const float* __restrict__ W, const float* __restrict__ bias,
    const int* __restrict__ pc, const float* __restrict__ pv,
    float* __restrict__ out)
{
  constexpr int FIN = 32;
  constexpr int F4 = FOUT / 4;
  constexpr size_t SLH = (size_t)N * 32 * FIN;   // halves per slice
  __shared__ float Ws[6 * FIN * FOUT];           // 24 KB or 48 KB
  for (int i = threadIdx.x; i < 6 * FIN * FOUT; i += 256) Ws[i] = W[i];
  __syncthreads();
  const float4* Ws4 = (const float4*)Ws;
  const float4* X4p = (const float4*)X;
  int t = blockIdx.x * 256 + threadIdx.x;        // exact grid: M*32*F4
  int fo4 = t % F4;
  int b   = (t / F4) % BATCH;
  int m   = t / (F4 * BATCH);
  int c0 = pc[m * 3 + 0], c1 = pc[m * 3 + 1], c2 = pc[m * 3 + 2];
  float v0 = pv[m * 3 + 0], v1 = pv[m * 3 + 1], v2 = pv[m * 3 + 2];
  float4 bi = ((const float4*)bias)[fo4];
  float4 a0 = bi, a1 = bi, a2 = bi;
  // k = 0 from fp32 X
  {
    const float4* r0 = X4p + ((size_t)c0 * BATCH + b) * 8;
    const float4* r1 = X4p + ((size_t)c1 * BATCH + b) * 8;
    const float4* r2 = X4p + ((size_t)c2 * BATCH + b) * 8;
#pragma unroll
    for (int fi = 0; fi < 8; ++fi) {
      float4 t0 = r0[fi], t1 = r1[fi], t2 = r2[fi];
#pragma unroll
      for (int ff = 0; ff < 4; ++ff) {
        float4 w = Ws4[(fi * 4 + ff) * F4 + fo4];
        fma4(a0, ((const float*)&t0)[ff], w);
        fma4(a1, ((const float*)&t1)[ff], w);
        fma4(a2, ((const float*)&t2)[ff], w);
      }
    }
  }
  // k = 1..5 from fp16 T
#pragma unroll 1
  for (int k = 1; k < 6; ++k) {
    const half4* base = (const half4*)(Th + (size_t)(k - 1) * SLH);
    const half4* r0 = base + ((size_t)c0 * 32 + b) * 8;
    const half4* r1 = base + ((size_t)c1 * 32 + b) * 8;
    const half4* r2 = base + ((size_t)c2 * 32 + b) * 8;
#pragma unroll
    for (int q = 0; q < 8; ++q) {
      float f0[4], f1[4], f2[4];
      h4f(r0[q], f0); h4f(r1[q], f1); h4f(r2[q], f2);
#pragma unroll
      for (int ff = 0; ff < 4; ++ff) {
        float4 w = Ws4[((k * 32) + q * 4 + ff) * F4 + fo4];
        fma4(a0, f0[ff], w);
        fma4(a1, f1[ff], w);
        fma4(a2, f2[ff], w);
      }
    }
  }
  a0 = relu4(a0); a1 = relu4(a1); a2 = relu4(a2);
  float4 acc;
  acc.x = v0*a0.x + v1*a1.x + v2*a2.x;
  acc.y = v0*a0.y + v1*a1.y + v2*a2.y;
  acc.z = v0*a0.z + v1*a1.z + v2*a2.z;
  acc.w = v0*a0.w + v1*a1.w + v2*a2.w;
  size_t oi = OUT_BM ? (((size_t)b * M + m) * F4 + fo4) : (((size_t)m * BATCH + b) * F4 + fo4);
  ((float4*)out)[oi] = acc;
}

// ---------------- encoder split-K partial ----------------
__global__ void __launch_bounds__(256) encoder_partial(
    const float* __restrict__ Xf, const float* __restrict__ encW,
    float* __restrict__ partial)
{
  int b  = blockIdx.x;        // 0..31
  int ks = blockIdx.y;        // 0..15
  int fo = threadIdx.x & 127;
  int half = threadIdx.x >> 7;
  const float* xr = Xf + b * 4096 + ks * 256 + half * 128;
  const float* w  = encW + (size_t)(ks * 256 + half * 128) * 128;
  float acc = 0.f;
#pragma unroll 8
  for (int i = 0; i < 128; ++i) acc += xr[i] * w[(size_t)i * 128 + fo];
  __shared__ float part[256];
  part[threadIdx.x] = acc;
  __syncthreads();
  if (half == 0) partial[(size_t)(b * 16 + ks) * 128 + fo] = part[fo] + part[128 + fo];
}

// ---------------- fused encoder-reduce + relu + classifier ----------------
__global__ void __launch_bounds__(128) encoder_reduce_cls(
    const float* __restrict__ partial, const float* __restrict__ encB,
    const float* __restrict__ clsW, const float* __restrict__ clsB,
    float* __restrict__ out)
{
  int b = blockIdx.x;           // 0..31
  int fo = threadIdx.x;         // 0..127
  float acc = encB[fo];
#pragma unroll
  for (int ks = 0; ks < 16; ++ks) acc += partial[(size_t)(b * 16 + ks) * 128 + fo];
  __shared__ float Hs[128];
  Hs[fo] = fmaxf(acc, 0.f);
  __syncthreads();
  if (fo < 10) {
    float s = clsB[fo];
#pragma unroll 4
    for (int f = 0; f < 128; ++f) s += Hs[f] * clsW[f * 10 + fo];
    out[b * 10 + fo] = s;
  }
}

extern "C" void kernel_launch(void* const* d_in, const int* in_sizes, int n_in,
                              void* d_out, int out_size, void* d_ws, size_t ws_size,
                              hipStream_t stream)
{
  const float* x   = (const float*)d_in[0];
  const int* ec0 = (const int*)d_in[2];
  const int* ec1 = (const int*)d_in[4];
  const int* ec2 = (const int*)d_in[6];
  const int* ec3 = (const int*)d_in[8];
  const int* pc0 = (const int*)d_in[10]; const float* pv0 = (const float*)d_in[11];
  const int* pc1 = (const int*)d_in[13]; const float* pv1 = (const float*)d_in[14];
  const int* pc2 = (const int*)d_in[16]; const float* pv2 = (const float*)d_in[17];
  const int* pc3 = (const int*)d_in[19]; const float* pv3 = (const float*)d_in[20];
  const float* W0 = (const float*)d_in[21]; const float* b0 = (const float*)d_in[22];
  const float* W1 = (const float*)d_in[23]; const float* b1 = (const float*)d_in[24];
  const float* W2 = (const float*)d_in[25]; const float* b2 = (const float*)d_in[26];
  const float* W3 = (const float*)d_in[27]; const float* b3 = (const float*)d_in[28];
  const float* encW = (const float*)d_in[29]; const float* encB = (const float*)d_in[30];
  const float* clsW = (const float*)d_in[31]; const float* clsB = (const float*)d_in[32];
  float* out = (float*)d_out;

  float* ws = (float*)d_ws;
  half4*  Xb = (half4*)ws;               // 524,288 cells (1,048,576 floats)
  __half* Th = (__half*)(ws + 1048576);  // 20,971,520 halves (10,485,760 floats)
  float* X1 = ws + 1048576 + 10485760;   // 4,194,304
  float* X2 = X1 + 4194304;              // 1,048,576
  float* X3 = X2 + 1048576;              // 262,144
  float* X4 = X3 + 262144;               // 131,072  ([32][4096])
  float* P  = X4 + 131072;               // 65,536

  const float cI = -1.0f / 6.0f;
  const float cS = -1.0f / 3.0f;
  dim3 blk(256);

  transpose_b<<<dim3(2048), blk, 0, stream>>>(x, Xb);

  // ================= layer 0: N=16384, M=4096, XCD-local fp16 chain =================
  {
    constexpr size_t S = (size_t)16384 * 32;   // half4 cells per slice
    half4* T4 = (half4*)Th;
    cheb_step_b<<<dim3(2048), blk, 0, stream>>>(Xb,       Xb,       ec0, T4,        cI,  0.f);
    cheb_step_b<<<dim3(2048), blk, 0, stream>>>(T4,       Xb,       ec0, T4 + S,    cS, -1.f);
    cheb_step_b<<<dim3(2048), blk, 0, stream>>>(T4 + S,   T4,       ec0, T4 + 2*S,  cS, -1.f);
    cheb_step_b<<<dim3(2048), blk, 0, stream>>>(T4 + 2*S, T4 + S,   ec0, T4 + 3*S,  cS, -1.f);
    cheb_step_b<<<dim3(2048), blk, 0, stream>>>(T4 + 3*S, T4 + 2*S, ec0, T4 + 4*S,  cS, -1.f);
    pool_conv_f3_b<<<dim3(4096), blk, 0, stream>>>(
        Xb, (const half4*)Th, W0, b0, pc0, pv0, X1);
  }
  // ================= layer 1: N=4096, F=32, M=1024 =================
  cheb_recur_h4<4096, 32, 1024, 4><<<dim3(256), dim3(1024), 0, stream>>>(X1, ec1, Th);
  pool_conv_v32_h<4096, 1024, 32, false><<<dim3(1024), blk, 0, stream>>>(
      X1, Th, W1, b1, pc1, pv1, X2);

  // ================= layer 2: N=1024, F=32, M=256 =================
  cheb_recur_h4<1024, 32, 256, 4><<<dim3(256), blk, 0, stream>>>(X2, ec2, Th);
  pool_conv_v32_h<1024, 256, 32, false><<<dim3(256), blk, 0, stream>>>(
      X2, Th, W2, b2, pc2, pv2, X3);

  // ================= layer 3: N=256, F=32, M=64, FOUT=64, batch-major out =================
  cheb_recur_h4<256, 32, 256, 4><<<dim3(256), blk, 0, stream>>>(X3, ec3, Th);
  pool_conv_v32_h<256, 64, 64, true><<<dim3(128), blk, 0, stream>>>(
      X3, Th, W3, b3, pc3, pv3, X4);

  // ================= head =================
  encoder_partial<<<dim3(32, 16), blk, 0, stream>>>(X4, encW, P);
  encoder_reduce_cls<<<dim3(32), dim3(128), 0, stream>>>(P, encB, clsW, clsB, out);
}

// Round 5
// 281.721 us; speedup vs baseline: 2.5775x; 1.0062x over previous
//
#include <hip/hip_runtime.h>
#include <hip/hip_fp16.h>
#include <cstddef>
#include <cstdint>

#define BATCH 32

// Workspace layout (floats):
//   Xh : [16384][32] half4 (node-major)            = 1,048,576 floats
//   Th : layer0: 5 slices [n][32] half4; layers1-3: [n][32][F] halves
//        region = 10,485,760 floats
//   X1 : 4,194,304   X2 : 1,048,576   X3 : 262,144
//   X4 : 131,072 ([32][4096] fp32, batch-major)
//   P  : 524,288  (encoder partials [b][128][128])

struct alignas(8) half4 { __half2 lo, hi; };

__device__ __forceinline__ void h4f(const half4 h, float f[4]) {
  float2 a = __half22float2(h.lo);
  float2 c = __half22float2(h.hi);
  f[0] = a.x; f[1] = a.y; f[2] = c.x; f[3] = c.y;
}
__device__ __forceinline__ void fma4(float4& a, float s, const float4& w) {
  a.x += s * w.x; a.y += s * w.y; a.z += s * w.z; a.w += s * w.w;
}
__device__ __forceinline__ float4 relu4(const float4& a) {
  return make_float4(fmaxf(a.x, 0.f), fmaxf(a.y, 0.f), fmaxf(a.z, 0.f), fmaxf(a.w, 0.f));
}

// ---------------- transpose x[b][n][3] -> Xh[n][32][4] fp16 (pad=0) ----------------
__global__ void __launch_bounds__(256) transpose_h(
    const float* __restrict__ x, half4* __restrict__ xh)
{
  int t = blockIdx.x * 256 + threadIdx.x;   // n*32 + b
  int n = t >> 5;
  int b = t & 31;
  const float* src = x + ((size_t)b * 16384 + n) * 3;
  half4 h;
  h.lo = __floats2half2_rn(src[0], src[1]);
  h.hi = __floats2half2_rn(src[2], 0.f);
  xh[t] = h;
}

// ---------------- fp16 Cheb step, layer 0: 2 cells/thread for 12-deep ILP ----------------
// Thread handles (n,b) and (n+8192,b): 12 independent L3 gathers in flight.
__global__ void __launch_bounds__(256) cheb_step_h2(
    const half4* __restrict__ Tin, const half4* __restrict__ Tpp,
    const int* __restrict__ ec, half4* __restrict__ Tout,
    float coef, float beta)
{
  int idx = blockIdx.x * 256 + threadIdx.x;   // 0..262143
  int n = idx >> 5;                           // 0..8191
  int b = idx & 31;
  int idx2 = idx + 262144;                    // node n+8192, same b
  const int* e  = ec + n * 6;
  const int* e2 = ec + (n + 8192) * 6;
  float s0 = 0.f, s1 = 0.f, s2 = 0.f;
  float u0 = 0.f, u1 = 0.f, u2 = 0.f;
#pragma unroll
  for (int d = 0; d < 6; ++d) {
    half4 v = Tin[(e[d]  << 5) | b];
    half4 w = Tin[(e2[d] << 5) | b];
    float2 a = __half22float2(v.lo);
    float2 c = __half22float2(v.hi);
    s0 += a.x; s1 += a.y; s2 += c.x;
    float2 aw = __half22float2(w.lo);
    float2 cw = __half22float2(w.hi);
    u0 += aw.x; u1 += aw.y; u2 += cw.x;
  }
  half4 p  = Tpp[idx];
  half4 p2 = Tpp[idx2];
  float2 pa = __half22float2(p.lo);
  float2 pc = __half22float2(p.hi);
  float2 qa = __half22float2(p2.lo);
  float2 qc = __half22float2(p2.hi);
  half4 o, o2;
  o.lo  = __floats2half2_rn(coef * s0 + beta * pa.x, coef * s1 + beta * pa.y);
  o.hi  = __floats2half2_rn(coef * s2 + beta * pc.x, 0.f);
  o2.lo = __floats2half2_rn(coef * u0 + beta * qa.x, coef * u1 + beta * qa.y);
  o2.hi = __floats2half2_rn(coef * u2 + beta * qc.x, 0.f);
  Tout[idx]  = o;
  Tout[idx2] = o2;
}

// ---------------- fused pool(relu(conv)), FIN=3, fp16 X/T (R1-verified) ----------------
template<int N, int M, int FOUT>
__global__ void __launch_bounds__(256) pool_conv_f3_h(
    const half4* __restrict__ Xh, const half4* __restrict__ T,   // slices of N*32 cells
    const float* __restrict__ W, const float* __restrict__ bias,
    const int* __restrict__ pc, const float* __restrict__ pv,
    float* __restrict__ out)
{
  constexpr int F4 = FOUT / 4;
  constexpr size_t SL = (size_t)N * 32;        // cells per slice
  __shared__ float Ws[6 * 3 * FOUT];
  for (int i = threadIdx.x; i < 6 * 3 * FOUT; i += 256) Ws[i] = W[i];
  __syncthreads();
  const float4* Ws4 = (const float4*)Ws;
  int t = blockIdx.x * 256 + threadIdx.x;      // exact grid: M*32*F4
  int fo4 = t % F4;
  int b   = (t / F4) % BATCH;
  int m   = t / (F4 * BATCH);
  int c0 = pc[m * 3 + 0], c1 = pc[m * 3 + 1], c2 = pc[m * 3 + 2];
  float v0 = pv[m * 3 + 0], v1 = pv[m * 3 + 1], v2 = pv[m * 3 + 2];
  float4 bi = ((const float4*)bias)[fo4];
  float4 a0 = bi, a1 = bi, a2 = bi;
#pragma unroll
  for (int k = 0; k < 6; ++k) {
    const half4* base = (k == 0) ? Xh : (T + (size_t)(k - 1) * SL);
    float r0[4], r1[4], r2[4];
    h4f(base[(c0 << 5) | b], r0);
    h4f(base[(c1 << 5) | b], r1);
    h4f(base[(c2 << 5) | b], r2);
#pragma unroll
    for (int f = 0; f < 3; ++f) {
      float4 w = Ws4[(k * 3 + f) * F4 + fo4];
      fma4(a0, r0[f], w);
      fma4(a1, r1[f], w);
      fma4(a2, r2[f], w);
    }
  }
  a0 = relu4(a0); a1 = relu4(a1); a2 = relu4(a2);
  float4 acc;
  acc.x = v0*a0.x + v1*a1.x + v2*a2.x;
  acc.y = v0*a0.y + v1*a1.y + v2*a2.y;
  acc.z = v0*a0.z + v1*a1.z + v2*a2.z;
  acc.w = v0*a0.w + v1*a1.w + v2*a2.w;
  ((float4*)out)[((size_t)m * BATCH + b) * F4 + fo4] = acc;   // node-major fp32
}

// ---------------- LDS-resident Cheb recurrence (layers 1-3): half4 cells ----------------
// 8 B cells: random gathers over 16 bank-pair groups (~4-way, 1.58x) vs
// float4's 8 quad-groups (~8-way, 2.94x). LDS 32 KB max. R2-verified pattern.
template<int N, int F, int THREADS, int MINW>
__global__ void __launch_bounds__(THREADS, MINW) cheb_recur_hh(
    const float* __restrict__ X,    // node-major fp32 [N][32][F]
    const int* __restrict__ ec,     // [N][6]
    __half* __restrict__ Th)        // 5 slices, [n][32][F] halves
{
  constexpr int NPT = N / THREADS;
  __shared__ half4 cur[N];                     // 8 B per node
  const float cI = -1.0f / 6.0f;
  const float cS = -1.0f / 3.0f;
  const int b = blockIdx.x & 31;
  const int fbase = (blockIdx.x >> 5) * 4;     // slab of 4 features
  constexpr size_t SLH = (size_t)N * 32 * F;   // halves per slice
  half4 prevv[NPT], newh[NPT];
#pragma unroll
  for (int i = 0; i < NPT; ++i) {
    int n = threadIdx.x + i * THREADS;
    float4 xv = *(const float4*)(X + ((size_t)n * 32 + b) * F + fbase);
    half4 h;
    h.lo = __floats2half2_rn(xv.x, xv.y);
    h.hi = __floats2half2_rn(xv.z, xv.w);
    cur[n] = h;
  }
  __syncthreads();
#pragma unroll 1
  for (int k = 1; k <= 5; ++k) {
    __half* Tk = Th + (size_t)(k - 1) * SLH;
#pragma unroll
    for (int i = 0; i < NPT; ++i) {
      int n = threadIdx.x + i * THREADS;
      const int2* e2 = (const int2*)(ec + n * 6);
      int2 ea = e2[0], eb = e2[1], ez = e2[2];
      int na[6];
      na[0] = ea.x; na[1] = ea.y; na[2] = eb.x;
      na[3] = eb.y; na[4] = ez.x; na[5] = ez.y;
      float s0 = 0.f, s1 = 0.f, s2 = 0.f, s3 = 0.f;
#pragma unroll
      for (int d = 0; d < 6; ++d) {
        half4 t = cur[na[d]];                  // ds_read_b64
        float2 a = __half22float2(t.lo);
        float2 c = __half22float2(t.hi);
        s0 += a.x; s1 += a.y; s2 += c.x; s3 += c.y;
      }
      float v0, v1, v2, v3;
      if (k == 1) {
        v0 = cI * s0; v1 = cI * s1; v2 = cI * s2; v3 = cI * s3;
      } else {
        float2 pa = __half22float2(prevv[i].lo);
        float2 pc = __half22float2(prevv[i].hi);
        v0 = cS * s0 - pa.x; v1 = cS * s1 - pa.y;
        v2 = cS * s2 - pc.x; v3 = cS * s3 - pc.y;
      }
      half4 h;
      h.lo = __floats2half2_rn(v0, v1);
      h.hi = __floats2half2_rn(v2, v3);
      newh[i] = h;
      *(half4*)(Tk + ((size_t)n * 32 + b) * F + fbase) = h;
    }
    __syncthreads();   // all gathers of T_{k-1} complete
#pragma unroll
    for (int i = 0; i < NPT; ++i) {
      int n = threadIdx.x + i * THREADS;
      prevv[i] = cur[n];                       // own slot still = T_{k-1}
      cur[n] = newh[i];                        // T_k -> cur
    }
    __syncthreads();
  }
}

// ---------------- fused pool(relu(conv)), FIN=32, fp16 T (R1-verified) ----------------
template<int N, int M, int FOUT, bool OUT_BM>
__global__ void __launch_bounds__(256) pool_conv_v32_h(
    const float* __restrict__ X, const __half* __restrict__ Th,
    const float* __restrict__ W, const float* __restrict__ bias,
    const int* __restrict__ pc, const float* __restrict__ pv,
    float* __restrict__ out)
{
  constexpr int FIN = 32;
  constexpr int F4 = FOUT / 4;
  constexpr size_t SLH = (size_t)N * 32 * FIN;   // halves per slice
  __shared__ float Ws[6 * FIN * FOUT];           // 24 KB or 48 KB
  for (int i = threadIdx.x; i < 6 * FIN * FOUT; i += 256) Ws[i] = W[i];
  __syncthreads();
  const float4* Ws4 = (const float4*)Ws;
  const float4* X4p = (const float4*)X;
  int t = blockIdx.x * 256 + threadIdx.x;        // exact grid: M*32*F4
  int fo4 = t % F4;
  int b   = (t / F4) % BATCH;
  int m   = t / (F4 * BATCH);
  int c0 = pc[m * 3 + 0], c1 = pc[m * 3 + 1], c2 = pc[m * 3 + 2];
  float v0 = pv[m * 3 + 0], v1 = pv[m * 3 + 1], v2 = pv[m * 3 + 2];
  float4 bi = ((const float4*)bias)[fo4];
  float4 a0 = bi, a1 = bi, a2 = bi;
  // k = 0 from fp32 X
  {
    const float4* r0 = X4p + ((size_t)c0 * BATCH + b) * 8;
    const float4* r1 = X4p + ((size_t)c1 * BATCH + b) * 8;
    const float4* r2 = X4p + ((size_t)c2 * BATCH + b) * 8;
#pragma unroll
    for (int fi = 0; fi < 8; ++fi) {
      float4 t0 = r0[fi], t1 = r1[fi], t2 = r2[fi];
#pragma unroll
      for (int ff = 0; ff < 4; ++ff) {
        float4 w = Ws4[(fi * 4 + ff) * F4 + fo4];
        fma4(a0, ((const float*)&t0)[ff], w);
        fma4(a1, ((const float*)&t1)[ff], w);
        fma4(a2, ((const float*)&t2)[ff], w);
      }
    }
  }
  // k = 1..5 from fp16 T
#pragma unroll 1
  for (int k = 1; k < 6; ++k) {
    const half4* base = (const half4*)(Th + (size_t)(k - 1) * SLH);
    const half4* r0 = base + ((size_t)c0 * 32 + b) * 8;
    const half4* r1 = base + ((size_t)c1 * 32 + b) * 8;
    const half4* r2 = base + ((size_t)c2 * 32 + b) * 8;
#pragma unroll
    for (int q = 0; q < 8; ++q) {
      float f0[4], f1[4], f2[4];
      h4f(r0[q], f0); h4f(r1[q], f1); h4f(r2[q], f2);
#pragma unroll
      for (int ff = 0; ff < 4; ++ff) {
        float4 w = Ws4[((k * 32) + q * 4 + ff) * F4 + fo4];
        fma4(a0, f0[ff], w);
        fma4(a1, f1[ff], w);
        fma4(a2, f2[ff], w);
      }
    }
  }
  a0 = relu4(a0); a1 = relu4(a1); a2 = relu4(a2);
  float4 acc;
  acc.x = v0*a0.x + v1*a1.x + v2*a2.x;
  acc.y = v0*a0.y + v1*a1.y + v2*a2.y;
  acc.z = v0*a0.z + v1*a1.z + v2*a2.z;
  acc.w = v0*a0.w + v1*a1.w + v2*a2.w;
  size_t oi = OUT_BM ? (((size_t)b * M + m) * F4 + fo4) : (((size_t)m * BATCH + b) * F4 + fo4);
  ((float4*)out)[oi] = acc;
}

// ---------------- weight-stationary encoder partial ----------------
// Block j (0..127) owns encW rows [32j, 32j+32) in registers (read ONCE:
// 2 MB total vs 64 MB batch-replicated). X4 reads are wave-uniform -> scalar.
// partial layout [b][j][fo] for coalesced reduce.
__global__ void __launch_bounds__(128) encoder_partial_ws(
    const float* __restrict__ Xf, const float* __restrict__ encW,
    float* __restrict__ partial)
{
  int j  = blockIdx.x;          // i-chunk 0..127
  int fo = threadIdx.x;         // 0..127
  int i0 = j * 32;
  float w[32];
#pragma unroll
  for (int i = 0; i < 32; ++i) w[i] = encW[(size_t)(i0 + i) * 128 + fo];
#pragma unroll 1
  for (int b = 0; b < 32; ++b) {
    const float* xr = Xf + b * 4096 + i0;     // wave-uniform -> s_loads
    float s = 0.f;
#pragma unroll
    for (int i = 0; i < 32; ++i) s += xr[i] * w[i];
    partial[((size_t)b * 128 + j) * 128 + fo] = s;
  }
}

// ---------------- fused encoder-reduce + relu + classifier ----------------
__global__ void __launch_bounds__(128) encoder_reduce_cls(
    const float* __restrict__ partial, const float* __restrict__ encB,
    const float* __restrict__ clsW, const float* __restrict__ clsB,
    float* __restrict__ out)
{
  int b = blockIdx.x;           // 0..31
  int fo = threadIdx.x;         // 0..127
  float acc = encB[fo];
#pragma unroll 8
  for (int j = 0; j < 128; ++j) acc += partial[((size_t)b * 128 + j) * 128 + fo];
  __shared__ float Hs[128];
  Hs[fo] = fmaxf(acc, 0.f);
  __syncthreads();
  if (fo < 10) {
    float s = clsB[fo];
#pragma unroll 4
    for (int f = 0; f < 128; ++f) s += Hs[f] * clsW[f * 10 + fo];
    out[b * 10 + fo] = s;
  }
}

extern "C" void kernel_launch(void* const* d_in, const int* in_sizes, int n_in,
                              void* d_out, int out_size, void* d_ws, size_t ws_size,
                              hipStream_t stream)
{
  const float* x   = (const float*)d_in[0];
  const int* ec0 = (const int*)d_in[2];
  const int* ec1 = (const int*)d_in[4];
  const int* ec2 = (const int*)d_in[6];
  const int* ec3 = (const int*)d_in[8];
  const int* pc0 = (const int*)d_in[10]; const float* pv0 = (const float*)d_in[11];
  const int* pc1 = (const int*)d_in[13]; const float* pv1 = (const float*)d_in[14];
  const int* pc2 = (const int*)d_in[16]; const float* pv2 = (const float*)d_in[17];
  const int* pc3 = (const int*)d_in[19]; const float* pv3 = (const float*)d_in[20];
  const float* W0 = (const float*)d_in[21]; const float* b0 = (const float*)d_in[22];
  const float* W1 = (const float*)d_in[23]; const float* b1 = (const float*)d_in[24];
  const float* W2 = (const float*)d_in[25]; const float* b2 = (const float*)d_in[26];
  const float* W3 = (const float*)d_in[27]; const float* b3 = (const float*)d_in[28];
  const float* encW = (const float*)d_in[29]; const float* encB = (const float*)d_in[30];
  const float* clsW = (const float*)d_in[31]; const float* clsB = (const float*)d_in[32];
  float* out = (float*)d_out;

  float* ws = (float*)d_ws;
  half4*  Xh = (half4*)ws;               // 524,288 cells (1,048,576 floats)
  __half* Th = (__half*)(ws + 1048576);  // 20,971,520 halves (10,485,760 floats)
  float* X1 = ws + 1048576 + 10485760;   // 4,194,304
  float* X2 = X1 + 4194304;              // 1,048,576
  float* X3 = X2 + 1048576;              // 262,144
  float* X4 = X3 + 262144;               // 131,072  ([32][4096])
  float* P  = X4 + 131072;               // 524,288  ([32][128][128])

  const float cI = -1.0f / 6.0f;
  const float cS = -1.0f / 3.0f;
  dim3 blk(256);

  transpose_h<<<dim3(2048), blk, 0, stream>>>(x, Xh);

  // ================= layer 0: N=16384, M=4096, fp16 chain (2 cells/thread) =================
  {
    constexpr size_t S = (size_t)16384 * 32;   // cells per slice
    half4* T4 = (half4*)Th;
    cheb_step_h2<<<dim3(1024), blk, 0, stream>>>(Xh,       Xh,       ec0, T4,        cI,  0.f);
    cheb_step_h2<<<dim3(1024), blk, 0, stream>>>(T4,       Xh,       ec0, T4 + S,    cS, -1.f);
    cheb_step_h2<<<dim3(1024), blk, 0, stream>>>(T4 + S,   T4,       ec0, T4 + 2*S,  cS, -1.f);
    cheb_step_h2<<<dim3(1024), blk, 0, stream>>>(T4 + 2*S, T4 + S,   ec0, T4 + 3*S,  cS, -1.f);
    cheb_step_h2<<<dim3(1024), blk, 0, stream>>>(T4 + 3*S, T4 + 2*S, ec0, T4 + 4*S,  cS, -1.f);
    pool_conv_f3_h<16384, 4096, 32><<<dim3(4096), blk, 0, stream>>>(
        Xh, (const half4*)Th, W0, b0, pc0, pv0, X1);
  }
  // ================= layer 1: N=4096, F=32, M=1024 =================
  cheb_recur_hh<4096, 32, 1024, 4><<<dim3(256), dim3(1024), 0, stream>>>(X1, ec1, Th);
  pool_conv_v32_h<4096, 1024, 32, false><<<dim3(1024), blk, 0, stream>>>(
      X1, Th, W1, b1, pc1, pv1, X2);

  // ================= layer 2: N=1024, F=32, M=256 =================
  cheb_recur_hh<1024, 32, 256, 4><<<dim3(256), blk, 0, stream>>>(X2, ec2, Th);
  pool_conv_v32_h<1024, 256, 32, false><<<dim3(256), blk, 0, stream>>>(
      X2, Th, W2, b2, pc2, pv2, X3);

  // ================= layer 3: N=256, F=32, M=64, FOUT=64, batch-major out =================
  cheb_recur_hh<256, 32, 256, 4><<<dim3(256), blk, 0, stream>>>(X3, ec3, Th);
  pool_conv_v32_h<256, 64, 64, true><<<dim3(128), blk, 0, stream>>>(
      X3, Th, W3, b3, pc3, pv3, X4);

  // ================= head =================
  encoder_partial_ws<<<dim3(128), dim3(128), 0, stream>>>(X4, encW, P);
  encoder_reduce_cls<<<dim3(32), dim3(128), 0, stream>>>(P, encB, clsW, clsB, out);
}